// Round 4
// baseline (72.078 us; speedup 1.0000x reference)
//
#include <hip/hip_runtime.h>
#include <hip/hip_bf16.h>

typedef __bf16 bf16x8 __attribute__((ext_vector_type(8)));
typedef float  f32x4  __attribute__((ext_vector_type(4)));
typedef float  f32x16 __attribute__((ext_vector_type(16)));

#define B_SZ 4096
#define I_SZ 512
#define O_SZ 64
#define E_SZ 128
#define BM   256
#define BK   64
#define G_EXP 8      // experts per workgroup (K-split group size)
#define EG_N  16     // expert groups
#define MT_N  16     // m tiles (4096/256)

// ---------------- prep: x f32 -> bf16 ----------------
__global__ void prep_x(const float* __restrict__ x, __bf16* __restrict__ xb) {
  int i = blockIdx.x * 256 + threadIdx.x;
  float4 v = ((const float4*)x)[i];
  union { __bf16 h[4]; ushort4 u4; } pk;
  pk.h[0] = (__bf16)v.x; pk.h[1] = (__bf16)v.y;
  pk.h[2] = (__bf16)v.z; pk.h[3] = (__bf16)v.w;
  ((ushort4*)xb)[i] = pk.u4;
}

// ---------------- prep: W [e][i][o] f32 -> wt [e][o][i] bf16 ----------------
__global__ void prep_w(const float* __restrict__ W, __bf16* __restrict__ wt) {
  __shared__ __bf16 tile[64][66];
  int e  = blockIdx.x >> 3;
  int it = blockIdx.x & 7;
  const float* src = W + (size_t)e * I_SZ * O_SZ + (size_t)it * 64 * O_SZ;
  #pragma unroll
  for (int s = 0; s < 16; ++s) {
    int idx = s * 256 + threadIdx.x;
    int r = idx >> 6, o = idx & 63;
    tile[o][r] = (__bf16)src[idx];
  }
  __syncthreads();
  __bf16* dst = wt + (size_t)e * O_SZ * I_SZ + it * 64;
  #pragma unroll
  for (int s = 0; s < 4; ++s) {
    int idx = s * 256 + threadIdx.x;
    int o = idx >> 4, c = (idx & 15) << 2;
    union { __bf16 h[4]; ushort4 u4; } q;
    q.h[0] = tile[o][c + 0]; q.h[1] = tile[o][c + 1];
    q.h[2] = tile[o][c + 2]; q.h[3] = tile[o][c + 3];
    *(ushort4*)&dst[(size_t)o * I_SZ + c] = q.u4;
  }
}

// ---------------- prep: gT[e][b] = dst[b][e>>2] * type[b][e&3] ----------------
__global__ void prep_g(const float* __restrict__ ds, const float* __restrict__ ts,
                       float* __restrict__ gT) {
  int idx = blockIdx.x * 256 + threadIdx.x;
  int e = idx >> 12, b = idx & 4095;
  gT[idx] = ds[b * 32 + (e >> 2)] * ts[b * 4 + (e & 3)];
}

// ---------------- main: x-in-registers, W-only LDS, deep-pipelined ----------------
// 8 waves x 32 rows = BM 256; mfma_f32_32x32x16_bf16, Nf=2 covers O=64.
// Swizzle: phys slot = logical slot ^ (o&7) ^ (bit4(o)<<2)  -- the bit-4 term
// rotates the slot base every 16 lanes of the reader (proven conflict-free
// quarter-rotation pattern from rounds 1-2); same involution on both sides.
__global__ __launch_bounds__(512, 2)
void mtc_gemm(const __bf16* __restrict__ xb, const __bf16* __restrict__ wt,
              const float* __restrict__ gT, float* __restrict__ partials) {
  __shared__ __align__(16) __bf16 wsh[4][O_SZ * BK];  // 4 x 8KB W buffers
  __shared__ float gsh[G_EXP][BM];                    // 8KB gates

  const int tid  = threadIdx.x;
  const int wave = tid >> 6;
  const int lane = tid & 63;

  // XCD swizzle: 256 blocks -> 32 consecutive per XCD
  int bid = (int)blockIdx.x;
  bid = (bid & 7) * 32 + (bid >> 3);
  const int mtile = bid & 15;
  const int eg    = bid >> 4;
  const int row0  = mtile * BM;
  const int e0    = eg * G_EXP;

  for (int idx = tid; idx < G_EXP * BM; idx += 512)
    gsh[idx >> 8][idx & 255] =
        gT[(size_t)(e0 + (idx >> 8)) * B_SZ + row0 + (idx & 255)];

  // x A-fragments in registers: lane holds row (lane&31), k = j*16 + (lane>>5)*8
  bf16x8 af[32];
  {
    const __bf16* xr = xb + (size_t)(row0 + wave * 32 + (lane & 31)) * I_SZ
                          + (lane >> 5) * 8;
    #pragma unroll
    for (int j = 0; j < 32; ++j)
      af[j] = *(const bf16x8*)(xr + j * 16);
  }

  // stage one W chunk (expert e, k-chunk kc) into wsh[sbuf].
  auto stage = [&](int sbuf, int e, int kc) {
    const __bf16* wsrc = wt + (size_t)(e0 + e) * O_SZ * I_SZ + kc * BK;
    int o = tid >> 3, p = tid & 7;
    int sl = p ^ (o & 7) ^ (((o >> 4) & 1) << 2);
    __builtin_amdgcn_global_load_lds(
        (const __attribute__((address_space(1))) void*)(wsrc + (size_t)o * I_SZ + sl * 8),
        (__attribute__((address_space(3))) void*)(&wsh[sbuf][wave * 512]),
        16, 0, 0);
  };

  __syncthreads();                     // drains x loads + gsh writes

  stage(0, 0, 0); stage(1, 0, 1); stage(2, 0, 2);
  asm volatile("s_waitcnt vmcnt(2)" ::: "memory");
  __builtin_amdgcn_s_barrier();

  f32x16 logits[2] = {};

  for (int e = 0; e < G_EXP; ++e) {
    f32x16 acc[2][2] = {};            // [nf][ks&1]: 4 independent MFMA chains
    #pragma unroll
    for (int kc = 0; kc < 8; ++kc) {
      const int ph = e * 8 + kc;                 // buf = kc & 3 (compile-time)
      if (ph + 3 < 64) {
        int np = ph + 3;
        stage((kc + 3) & 3, np >> 3, np & 7);
      }
      const __bf16* wb = &wsh[kc & 3][0];
      __builtin_amdgcn_s_setprio(1);
      #pragma unroll
      for (int ks = 0; ks < 4; ++ks) {
        bf16x8 bfr[2];
        #pragma unroll
        for (int nf = 0; nf < 2; ++nf) {
          int o  = nf * 32 + (lane & 31);
          int p  = ks * 2 + (lane >> 5);
          int sl = p ^ (o & 7) ^ (((o >> 4) & 1) << 2);
          bfr[nf] = *(const bf16x8*)(wb + o * BK + sl * 8);
        }
        #pragma unroll
        for (int nf = 0; nf < 2; ++nf)
          acc[nf][ks & 1] = __builtin_amdgcn_mfma_f32_32x32x16_bf16(
              af[kc * 4 + ks], bfr[nf], acc[nf][ks & 1], 0, 0, 0);
      }
      __builtin_amdgcn_s_setprio(0);
      // counted wait: keep 2 newest stages in flight; exact tail at e==7
      if (ph + 3 < 64) {
        asm volatile("s_waitcnt vmcnt(2)" ::: "memory");
      } else if (kc == 5) {
        asm volatile("s_waitcnt vmcnt(1)" ::: "memory");
      } else if (kc == 6) {
        asm volatile("s_waitcnt vmcnt(0)" ::: "memory");
      }
      if (ph != 63) __builtin_amdgcn_s_barrier();
    }
    // drain: logits += g[row,e] * (acc0+acc1).
    // C/D: col=lane&31, row=(rg&3)+8*(rg>>2)+4*(lane>>5)
    f32x4 gq[4];
    #pragma unroll
    for (int q = 0; q < 4; ++q)
      gq[q] = *(const f32x4*)&gsh[e][wave * 32 + q * 8 + (lane >> 5) * 4];
    #pragma unroll
    for (int nf = 0; nf < 2; ++nf)
      #pragma unroll
      for (int rg = 0; rg < 16; ++rg)
        logits[nf][rg] += gq[rg >> 2][rg & 3] * (acc[nf][0][rg] + acc[nf][1][rg]);
  }

  float* pout = partials + (size_t)eg * B_SZ * O_SZ + (size_t)row0 * O_SZ;
  #pragma unroll
  for (int nf = 0; nf < 2; ++nf)
    #pragma unroll
    for (int rg = 0; rg < 16; ++rg) {
      int r = wave * 32 + (rg & 3) + 8 * (rg >> 2) + 4 * (lane >> 5);
      int o = nf * 32 + (lane & 31);
      pout[(size_t)r * O_SZ + o] = logits[nf][rg];
    }
}

// ---------------- reduce: sum partials + gated bias + log_softmax ----------------
__global__ __launch_bounds__(256)
void mtc_reduce(const float* __restrict__ partials, const float* __restrict__ gT,
                const float* __restrict__ bias, float* __restrict__ out) {
  __shared__ float bsh[E_SZ * O_SZ];                // 32 KB
  for (int i = threadIdx.x; i < E_SZ * O_SZ; i += 256) bsh[i] = bias[i];
  __syncthreads();
  int wave = threadIdx.x >> 6, lane = threadIdx.x & 63;
  int r = blockIdx.x * 4 + wave;
  float s = 0.f;
  #pragma unroll
  for (int k = 0; k < EG_N; ++k)
    s += partials[(size_t)k * B_SZ * O_SZ + (size_t)r * O_SZ + lane];
  float bacc = 0.f;
  for (int e = 0; e < E_SZ; ++e)
    bacc += gT[(size_t)e * B_SZ + r] * bsh[e * O_SZ + lane];
  s += bacc;
  float m = s;
  #pragma unroll
  for (int off = 32; off; off >>= 1) m = fmaxf(m, __shfl_xor(m, off));
  float ex = expf(s - m), sum = ex;
  #pragma unroll
  for (int off = 32; off; off >>= 1) sum += __shfl_xor(sum, off);
  out[(size_t)r * O_SZ + lane] = s - m - logf(sum);
}

extern "C" void kernel_launch(void* const* d_in, const int* in_sizes, int n_in,
                              void* d_out, int out_size, void* d_ws, size_t ws_size,
                              hipStream_t stream) {
  const float* x    = (const float*)d_in[0];
  const float* ds   = (const float*)d_in[1];
  const float* ts   = (const float*)d_in[2];
  const float* W    = (const float*)d_in[3];
  const float* bias = (const float*)d_in[4];
  float* out = (float*)d_out;

  char* w = (char*)d_ws;
  __bf16* xb      = (__bf16*)(w);                   // 4 MB
  __bf16* wt      = (__bf16*)(w + (4ull  << 20));   // 8 MB
  float*  gT      = (float*) (w + (12ull << 20));   // 2 MB
  float*  parts   = (float*) (w + (14ull << 20));   // 16 MB

  prep_x    <<<2048, 256, 0, stream>>>(x, xb);
  prep_w    <<<1024, 256, 0, stream>>>(W, wt);
  prep_g    <<<2048, 256, 0, stream>>>(ds, ts, gT);
  mtc_gemm  <<< 256, 512, 0, stream>>>(xb, wt, gT, parts);
  mtc_reduce<<<1024, 256, 0, stream>>>(parts, gT, bias, out);
}

// Round 5
// 66.712 us; speedup vs baseline: 1.0804x; 1.0804x over previous
//
#include <hip/hip_runtime.h>
#include <hip/hip_bf16.h>

typedef __bf16 bf16x8 __attribute__((ext_vector_type(8)));
typedef float  f32x4  __attribute__((ext_vector_type(4)));

#define B_SZ 4096
#define I_SZ 512
#define O_SZ 64
#define E_SZ 128
#define BM   256
#define G_EXP 8      // experts per workgroup (K-split group size)
#define EG_N  16     // expert groups
#define MT_N  16     // m tiles (4096/256)

// ---------------- prep: x f32 -> bf16 ----------------
__global__ void prep_x(const float* __restrict__ x, __bf16* __restrict__ xb) {
  int i = blockIdx.x * 256 + threadIdx.x;
  float4 v = ((const float4*)x)[i];
  union { __bf16 h[4]; ushort4 u4; } pk;
  pk.h[0] = (__bf16)v.x; pk.h[1] = (__bf16)v.y;
  pk.h[2] = (__bf16)v.z; pk.h[3] = (__bf16)v.w;
  ((ushort4*)xb)[i] = pk.u4;
}

// ---------------- prep: W [e][i][o] f32 -> wt [e][o][i] bf16 ----------------
__global__ void prep_w(const float* __restrict__ W, __bf16* __restrict__ wt) {
  __shared__ __bf16 tile[64][66];
  int e  = blockIdx.x >> 3;
  int it = blockIdx.x & 7;
  const float* src = W + (size_t)e * I_SZ * O_SZ + (size_t)it * 64 * O_SZ;
  #pragma unroll
  for (int s = 0; s < 16; ++s) {
    int idx = s * 256 + threadIdx.x;
    int r = idx >> 6, o = idx & 63;
    tile[o][r] = (__bf16)src[idx];
  }
  __syncthreads();
  __bf16* dst = wt + (size_t)e * O_SZ * I_SZ + it * 64;
  #pragma unroll
  for (int s = 0; s < 4; ++s) {
    int idx = s * 256 + threadIdx.x;
    int o = idx >> 4, c = (idx & 15) << 2;
    union { __bf16 h[4]; ushort4 u4; } q;
    q.h[0] = tile[o][c + 0]; q.h[1] = tile[o][c + 1];
    q.h[2] = tile[o][c + 2]; q.h[3] = tile[o][c + 3];
    *(ushort4*)&dst[(size_t)o * I_SZ + c] = q.u4;
  }
}

// ---------------- prep: gT[e][b] = dst[b][e>>2] * type[b][e&3] ----------------
__global__ void prep_g(const float* __restrict__ ds, const float* __restrict__ ts,
                       float* __restrict__ gT) {
  int idx = blockIdx.x * 256 + threadIdx.x;
  int e = idx >> 12, b = idx & 4095;
  gT[idx] = ds[b * 32 + (e >> 2)] * ts[b * 4 + (e & 3)];
}

// ---------------- main: fat phases (1 expert = 64KB W per phase) ----------------
// 8 waves x 32 rows (Mf=2 of 16) = BM 256; mfma_f32_16x16x32_bf16, Nf=4 covers O=64.
// x in registers (af[2][16]); W double-buffered 2x64KB in LDS; 8 phases total.
// Swizzle = rounds-1/2 measured-zero-conflict geometry: phys_slot = q ^ (o&7),
// reader slot base q = j*4 + (lane>>4) rotates per 16-lane quarter.
__global__ __launch_bounds__(512, 2)
void mtc_gemm(const __bf16* __restrict__ xb, const __bf16* __restrict__ wt,
              const float* __restrict__ gT, float* __restrict__ partials) {
  __shared__ __align__(16) __bf16 wsh[2][O_SZ * I_SZ];  // 2 x 64KB expert buffers
  __shared__ float gsh[G_EXP][BM];                      // 8KB gates

  const int tid  = threadIdx.x;
  const int wave = tid >> 6;
  const int lane = tid & 63;

  // XCD swizzle: 256 blocks -> 32 consecutive per XCD
  int bid = (int)blockIdx.x;
  bid = (bid & 7) * 32 + (bid >> 3);
  const int mtile = bid & 15;
  const int eg    = bid >> 4;
  const int row0  = mtile * BM;
  const int e0    = eg * G_EXP;

  for (int idx = tid; idx < G_EXP * BM; idx += 512)
    gsh[idx >> 8][idx & 255] =
        gT[(size_t)(e0 + (idx >> 8)) * B_SZ + row0 + (idx & 255)];

  // x A-fragments: af[mf][j] = x[row0+wave*32+mf*16+(lane&15)][j*32+(lane>>4)*8 ..+8]
  bf16x8 af[2][16];
  {
    const __bf16* xr = xb + (size_t)(row0 + wave * 32 + (lane & 15)) * I_SZ
                          + (lane >> 4) * 8;
    #pragma unroll
    for (int mf = 0; mf < 2; ++mf)
      #pragma unroll
      for (int j = 0; j < 16; ++j)
        af[mf][j] = *(const bf16x8*)(xr + mf * 16 * I_SZ + j * 32);
  }

  // stage whole expert e into wsh[sbuf]: 8 loads/thread, each load = one 1KB row.
  // lane holds phys slot `lane` of row o = i*8+wave; content = logical slot
  // q = lane ^ (o&7)  (involution; read applies same XOR).
  auto stage = [&](int sbuf, int e) {
    const __bf16* wsrc = wt + (size_t)(e0 + e) * O_SZ * I_SZ;
    #pragma unroll
    for (int i = 0; i < 8; ++i) {
      int o = i * 8 + wave;
      int q = lane ^ (o & 7);
      __builtin_amdgcn_global_load_lds(
          (const __attribute__((address_space(1))) void*)(wsrc + (size_t)o * I_SZ + q * 8),
          (__attribute__((address_space(3))) void*)(&wsh[sbuf][o * I_SZ]),
          16, 0, 0);
    }
  };

  __syncthreads();                     // gsh writes + af loads drained

  stage(0, 0);

  f32x4 logits[2][4] = {};

  int buf = 0;
  for (int e = 0; e < G_EXP; ++e) {
    if (e < G_EXP - 1) {
      stage(buf ^ 1, e + 1);                       // 8 loads into other buffer
      asm volatile("s_waitcnt vmcnt(8)" ::: "memory");   // stage(e) complete
    } else {
      asm volatile("s_waitcnt vmcnt(0)" ::: "memory");
    }
    __builtin_amdgcn_s_barrier();                  // buf ready for all waves

    f32x4 acc[2][4] = {};
    const __bf16* wb = &wsh[buf][0];
    __builtin_amdgcn_s_setprio(1);
    #pragma unroll
    for (int j = 0; j < 16; ++j) {                 // K-steps of 32
      bf16x8 bfr[4];
      #pragma unroll
      for (int nf = 0; nf < 4; ++nf) {
        int o  = nf * 16 + (lane & 15);
        int q  = j * 4 + (lane >> 4);
        int ph = q ^ (o & 7);
        bfr[nf] = *(const bf16x8*)(wb + (size_t)o * I_SZ + ph * 8);
      }
      #pragma unroll
      for (int nf = 0; nf < 4; ++nf)
        #pragma unroll
        for (int mf = 0; mf < 2; ++mf)
          acc[mf][nf] = __builtin_amdgcn_mfma_f32_16x16x32_bf16(
              af[mf][j], bfr[nf], acc[mf][nf], 0, 0, 0);
    }
    __builtin_amdgcn_s_setprio(0);

    // drain: logits += g[row,e] * acc.  C/D: col=lane&15, row=(lane>>4)*4+rg
    f32x4 gq[2];
    #pragma unroll
    for (int mf = 0; mf < 2; ++mf)
      gq[mf] = *(const f32x4*)&gsh[e][wave * 32 + mf * 16 + (lane >> 4) * 4];
    #pragma unroll
    for (int mf = 0; mf < 2; ++mf)
      #pragma unroll
      for (int nf = 0; nf < 4; ++nf)
        #pragma unroll
        for (int rg = 0; rg < 4; ++rg)
          logits[mf][nf][rg] += gq[mf][rg] * acc[mf][nf][rg];

    __builtin_amdgcn_s_barrier();                  // all waves done reading buf
    buf ^= 1;
  }

  float* pout = partials + (size_t)eg * B_SZ * O_SZ + (size_t)row0 * O_SZ;
  #pragma unroll
  for (int mf = 0; mf < 2; ++mf)
    #pragma unroll
    for (int nf = 0; nf < 4; ++nf)
      #pragma unroll
      for (int rg = 0; rg < 4; ++rg) {
        int r = wave * 32 + mf * 16 + ((lane >> 4) << 2) + rg;
        int o = nf * 16 + (lane & 15);
        pout[(size_t)r * O_SZ + o] = logits[mf][nf][rg];
      }
}

// ---------------- reduce: sum partials + gated bias + log_softmax ----------------
__global__ __launch_bounds__(256)
void mtc_reduce(const float* __restrict__ partials, const float* __restrict__ gT,
                const float* __restrict__ bias, float* __restrict__ out) {
  __shared__ float bsh[E_SZ * O_SZ];                // 32 KB
  for (int i = threadIdx.x; i < E_SZ * O_SZ; i += 256) bsh[i] = bias[i];
  __syncthreads();
  int wave = threadIdx.x >> 6, lane = threadIdx.x & 63;
  int r = blockIdx.x * 4 + wave;
  float s = 0.f;
  #pragma unroll
  for (int k = 0; k < EG_N; ++k)
    s += partials[(size_t)k * B_SZ * O_SZ + (size_t)r * O_SZ + lane];
  float bacc = 0.f;
  for (int e = 0; e < E_SZ; ++e)
    bacc += gT[(size_t)e * B_SZ + r] * bsh[e * O_SZ + lane];
  s += bacc;
  float m = s;
  #pragma unroll
  for (int off = 32; off; off >>= 1) m = fmaxf(m, __shfl_xor(m, off));
  float ex = expf(s - m), sum = ex;
  #pragma unroll
  for (int off = 32; off; off >>= 1) sum += __shfl_xor(sum, off);
  out[(size_t)r * O_SZ + lane] = s - m - logf(sum);
}

extern "C" void kernel_launch(void* const* d_in, const int* in_sizes, int n_in,
                              void* d_out, int out_size, void* d_ws, size_t ws_size,
                              hipStream_t stream) {
  const float* x    = (const float*)d_in[0];
  const float* ds   = (const float*)d_in[1];
  const float* ts   = (const float*)d_in[2];
  const float* W    = (const float*)d_in[3];
  const float* bias = (const float*)d_in[4];
  float* out = (float*)d_out;

  char* w = (char*)d_ws;
  __bf16* xb      = (__bf16*)(w);                   // 4 MB
  __bf16* wt      = (__bf16*)(w + (4ull  << 20));   // 8 MB
  float*  gT      = (float*) (w + (12ull << 20));   // 2 MB
  float*  parts   = (float*) (w + (14ull << 20));   // 16 MB

  prep_x    <<<2048, 256, 0, stream>>>(x, xb);
  prep_w    <<<1024, 256, 0, stream>>>(W, wt);
  prep_g    <<<2048, 256, 0, stream>>>(ds, ts, gT);
  mtc_gemm  <<< 256, 512, 0, stream>>>(xb, wt, gT, parts);
  mtc_reduce<<<1024, 256, 0, stream>>>(parts, gT, bias, out);
}

// Round 6
// 63.527 us; speedup vs baseline: 1.1346x; 1.0501x over previous
//
#include <hip/hip_runtime.h>
#include <hip/hip_bf16.h>

typedef __bf16 bf16x8 __attribute__((ext_vector_type(8)));
typedef float  f32x4  __attribute__((ext_vector_type(4)));

#define B_SZ 4096
#define I_SZ 512
#define O_SZ 64
#define E_SZ 128
#define BM   256
#define G_EXP 8      // experts per workgroup (K-split group size)
#define EG_N  16     // expert groups
#define MT_N  16     // m tiles (4096/256)

// ---------------- fused prep: x f32->bf16  +  gT[e][b] ----------------
__global__ void prep_xg(const float* __restrict__ x, __bf16* __restrict__ xb,
                        const float* __restrict__ ds, const float* __restrict__ ts,
                        float* __restrict__ gT) {
  int i = blockIdx.x * 256 + threadIdx.x;          // 524288 = B*I/4 = E*B
  float4 v = ((const float4*)x)[i];
  union { __bf16 h[4]; ushort4 u4; } pk;
  pk.h[0] = (__bf16)v.x; pk.h[1] = (__bf16)v.y;
  pk.h[2] = (__bf16)v.z; pk.h[3] = (__bf16)v.w;
  ((ushort4*)xb)[i] = pk.u4;
  int e = i >> 12, b = i & 4095;
  gT[i] = ds[b * 32 + (e >> 2)] * ts[b * 4 + (e & 3)];
}

// ---------------- prep: W [e][i][o] f32 -> wt [e][o][i] bf16 ----------------
__global__ void prep_w(const float* __restrict__ W, __bf16* __restrict__ wt) {
  __shared__ __bf16 tile[64][66];
  int e  = blockIdx.x >> 3;
  int it = blockIdx.x & 7;
  const float* src = W + (size_t)e * I_SZ * O_SZ + (size_t)it * 64 * O_SZ;
  #pragma unroll
  for (int s = 0; s < 16; ++s) {
    int idx = s * 256 + threadIdx.x;
    int r = idx >> 6, o = idx & 63;
    tile[o][r] = (__bf16)src[idx];
  }
  __syncthreads();
  __bf16* dst = wt + (size_t)e * O_SZ * I_SZ + it * 64;
  #pragma unroll
  for (int s = 0; s < 4; ++s) {
    int idx = s * 256 + threadIdx.x;
    int o = idx >> 4, c = (idx & 15) << 2;
    union { __bf16 h[4]; ushort4 u4; } q;
    q.h[0] = tile[o][c + 0]; q.h[1] = tile[o][c + 1];
    q.h[2] = tile[o][c + 2]; q.h[3] = tile[o][c + 3];
    *(ushort4*)&dst[(size_t)o * I_SZ + c] = q.u4;
  }
}

// ---------------- main: fat expert phases, m201-style sub-phased ----------------
// 8 waves x 32 rows (Mf=2 of 16) = BM 256; mfma_f32_16x16x32_bf16, Nf=4 covers O=64.
// Per expert: 4 sub-phases, each {issue 2 stage-DMAs for e+1 | 16 ds_read_b128 |
// setprio(1) 32-MFMA cluster setprio(0) | s_barrier}. Boundary: counted work is
// already landed -> vmcnt(0) is cheap; 2x64KB double buffer.
// Bias folded into accumulator init: acc = b[e][o]; drain logits += g*(xW+b).
__global__ __launch_bounds__(512, 2)
void mtc_gemm(const __bf16* __restrict__ xb, const __bf16* __restrict__ wt,
              const float* __restrict__ gT, const float* __restrict__ bias,
              float* __restrict__ partials) {
  __shared__ __align__(16) __bf16 wsh[2][O_SZ * I_SZ];  // 2 x 64KB expert buffers
  __shared__ float gsh[G_EXP][BM];                      // 8KB gates

  const int tid  = threadIdx.x;
  const int wave = tid >> 6;
  const int lane = tid & 63;

  // XCD swizzle: 256 blocks -> 32 consecutive per XCD
  int bid = (int)blockIdx.x;
  bid = (bid & 7) * 32 + (bid >> 3);
  const int mtile = bid & 15;
  const int eg    = bid >> 4;
  const int row0  = mtile * BM;
  const int e0    = eg * G_EXP;

  // stage slice s (2 of 8 rows-of-8) of expert e into wsh[sbuf].
  // phys slot `lane` of row o holds logical slot lane^(o&7) (involution).
  auto stage2 = [&](int sbuf, int e, int s) {
    const __bf16* wsrc = wt + (size_t)(e0 + e) * O_SZ * I_SZ;
    #pragma unroll
    for (int ii = 0; ii < 2; ++ii) {
      int o = (s * 2 + ii) * 8 + wave;
      int q = lane ^ (o & 7);
      __builtin_amdgcn_global_load_lds(
          (const __attribute__((address_space(1))) void*)(wsrc + (size_t)o * I_SZ + q * 8),
          (__attribute__((address_space(3))) void*)(&wsh[sbuf][o * I_SZ]),
          16, 0, 0);
    }
  };

  // prologue: stage expert 0 fully, overlap with gsh + af loads
  #pragma unroll
  for (int s = 0; s < 4; ++s) stage2(0, 0, s);

  for (int idx = tid; idx < G_EXP * BM; idx += 512)
    gsh[idx >> 8][idx & 255] =
        gT[(size_t)(e0 + (idx >> 8)) * B_SZ + row0 + (idx & 255)];

  // x A-fragments: af[mf][j] = x[row0+wave*32+mf*16+(lane&15)][j*32+(lane>>4)*8 ..+8]
  bf16x8 af[2][16];
  {
    const __bf16* xr = xb + (size_t)(row0 + wave * 32 + (lane & 15)) * I_SZ
                          + (lane >> 4) * 8;
    #pragma unroll
    for (int mf = 0; mf < 2; ++mf)
      #pragma unroll
      for (int j = 0; j < 16; ++j)
        af[mf][j] = *(const bf16x8*)(xr + mf * 16 * I_SZ + j * 32);
  }

  __syncthreads();                     // drains DMA(e0) + af + gsh

  f32x4 logits[2][4] = {};
  int buf = 0;
  for (int e = 0; e < G_EXP; ++e) {
    // bias -> accumulator init (4 scalar f32, tiny & L2-hot)
    float bv[4];
    #pragma unroll
    for (int nf = 0; nf < 4; ++nf)
      bv[nf] = bias[(size_t)(e0 + e) * O_SZ + nf * 16 + (lane & 15)];
    f32x4 acc[2][4];
    #pragma unroll
    for (int mf = 0; mf < 2; ++mf)
      #pragma unroll
      for (int nf = 0; nf < 4; ++nf)
        acc[mf][nf] = (f32x4){bv[nf], bv[nf], bv[nf], bv[nf]};

    const __bf16* wb = &wsh[buf][0];
    #pragma unroll
    for (int s = 0; s < 4; ++s) {
      if (e < G_EXP - 1) stage2(buf ^ 1, e + 1, s);   // 2 DMAs this sub-phase
      __builtin_amdgcn_s_setprio(1);
      #pragma unroll
      for (int jj = 0; jj < 4; ++jj) {               // 4 K32-steps per sub-phase
        const int j = s * 4 + jj;
        bf16x8 bfr[4];
        #pragma unroll
        for (int nf = 0; nf < 4; ++nf) {
          int o  = nf * 16 + (lane & 15);
          int q  = j * 4 + (lane >> 4);
          int ph = q ^ (o & 7);
          bfr[nf] = *(const bf16x8*)(wb + (size_t)o * I_SZ + ph * 8);
        }
        #pragma unroll
        for (int nf = 0; nf < 4; ++nf)
          #pragma unroll
          for (int mf = 0; mf < 2; ++mf)
            acc[mf][nf] = __builtin_amdgcn_mfma_f32_16x16x32_bf16(
                af[mf][j], bfr[nf], acc[mf][nf], 0, 0, 0);
      }
      __builtin_amdgcn_s_setprio(0);
      __builtin_amdgcn_s_barrier();                  // sub-phase alignment
    }

    // drain: logits += g[row,e] * acc.  C/D: col=lane&15, row=(lane>>4)*4+rg
    f32x4 gq[2];
    #pragma unroll
    for (int mf = 0; mf < 2; ++mf)
      gq[mf] = *(const f32x4*)&gsh[e][wave * 32 + mf * 16 + (lane >> 4) * 4];
    #pragma unroll
    for (int mf = 0; mf < 2; ++mf)
      #pragma unroll
      for (int nf = 0; nf < 4; ++nf)
        #pragma unroll
        for (int rg = 0; rg < 4; ++rg)
          logits[mf][nf][rg] += gq[mf][rg] * acc[mf][nf][rg];

    asm volatile("s_waitcnt vmcnt(0)" ::: "memory"); // stage(e+1) landed (cheap)
    __builtin_amdgcn_s_barrier();
    buf ^= 1;
  }

  float* pout = partials + (size_t)eg * B_SZ * O_SZ + (size_t)row0 * O_SZ;
  #pragma unroll
  for (int mf = 0; mf < 2; ++mf)
    #pragma unroll
    for (int nf = 0; nf < 4; ++nf)
      #pragma unroll
      for (int rg = 0; rg < 4; ++rg) {
        int r = wave * 32 + mf * 16 + ((lane >> 4) << 2) + rg;
        int o = nf * 16 + (lane & 15);
        pout[(size_t)r * O_SZ + o] = logits[mf][nf][rg];
      }
}

// ---------------- reduce: sum partials + log_softmax (bias already in gemm) ----
__global__ __launch_bounds__(256)
void mtc_reduce(const float* __restrict__ partials, float* __restrict__ out) {
  int wave = threadIdx.x >> 6, lane = threadIdx.x & 63;
  int r = blockIdx.x * 4 + wave;                    // one 64-lane wave per row
  float s = 0.f;
  #pragma unroll
  for (int k = 0; k < EG_N; ++k)
    s += partials[(size_t)k * B_SZ * O_SZ + (size_t)r * O_SZ + lane];
  float m = s;
  #pragma unroll
  for (int off = 32; off; off >>= 1) m = fmaxf(m, __shfl_xor(m, off));
  float ex = expf(s - m), sum = ex;
  #pragma unroll
  for (int off = 32; off; off >>= 1) sum += __shfl_xor(sum, off);
  out[(size_t)r * O_SZ + lane] = s - m - logf(sum);
}

extern "C" void kernel_launch(void* const* d_in, const int* in_sizes, int n_in,
                              void* d_out, int out_size, void* d_ws, size_t ws_size,
                              hipStream_t stream) {
  const float* x    = (const float*)d_in[0];
  const float* ds   = (const float*)d_in[1];
  const float* ts   = (const float*)d_in[2];
  const float* W    = (const float*)d_in[3];
  const float* bias = (const float*)d_in[4];
  float* out = (float*)d_out;

  char* w = (char*)d_ws;
  __bf16* xb      = (__bf16*)(w);                   // 4 MB
  __bf16* wt      = (__bf16*)(w + (4ull  << 20));   // 8 MB
  float*  gT      = (float*) (w + (12ull << 20));   // 2 MB
  float*  parts   = (float*) (w + (14ull << 20));   // 16 MB

  prep_xg   <<<2048, 256, 0, stream>>>(x, xb, ds, ts, gT);
  prep_w    <<<1024, 256, 0, stream>>>(W, wt);
  mtc_gemm  <<< 256, 512, 0, stream>>>(xb, wt, gT, bias, parts);
  mtc_reduce<<<1024, 256, 0, stream>>>(parts, out);
}